// Round 7
// baseline (516.432 us; speedup 1.0000x reference)
//
#include <hip/hip_runtime.h>
#include <hip/hip_bf16.h>
#include <math.h>

// ---------------------------------------------------------------------------
// BitNet-b1.58 MLP: x -> bitlinear(W1,b1) -> gelu(erf) -> bitlinear(W2,b2)
// Exact-integer formulation: int8 x int8 -> int32 MFMA, dequant in epilogue.
// GEMM r7: 128x128 tile, BK=128, 4 waves, dbuf LDS 64KB -> 2 blocks/CU.
// Co-resident blocks fill each other's sync gaps. Counted vmcnt(8) (stage
// t+1 issued before the wait), 2 barriers/tile, XOR swizzle (row&7)<<4,
// global_load_lds w16, setprio, XCD-chunked block swizzle.
// ---------------------------------------------------------------------------

typedef int int32x4 __attribute__((ext_vector_type(4)));

typedef const void __attribute__((address_space(1))) gv_t;
typedef void __attribute__((address_space(3))) lv_t;

__device__ __forceinline__ void gload_lds16(const signed char* g,
                                            signed char* l) {
  __builtin_amdgcn_global_load_lds((gv_t*)g, (lv_t*)l, 16, 0, 0);
}

__device__ __forceinline__ float gelu_erf(float v) {
  return 0.5f * v * (1.0f + erff(v * 0.70710678118654752440f));
}

__device__ __forceinline__ void store_gt(float* p, float v) { *p = v; }
__device__ __forceinline__ void store_gt(__hip_bfloat16* p, float v) {
  unsigned u = __float_as_uint(v);
  u += 0x7fffu + ((u >> 16) & 1u);  // RNE to bf16
  *(unsigned short*)p = (unsigned short)(u >> 16);
}

__device__ __forceinline__ void load4v(const float* p, float v[4]) {
  const float4 t = *(const float4*)p;
  v[0] = t.x; v[1] = t.y; v[2] = t.z; v[3] = t.w;
}
__device__ __forceinline__ void load4v(const __hip_bfloat16* p, float v[4]) {
  const ushort4 t = *(const ushort4*)p;
  v[0] = __uint_as_float((unsigned)t.x << 16);
  v[1] = __uint_as_float((unsigned)t.y << 16);
  v[2] = __uint_as_float((unsigned)t.z << 16);
  v[3] = __uint_as_float((unsigned)t.w << 16);
}

// --------------------------- w_scale reduction ------------------------------
__global__ __launch_bounds__(256) void absmean_partial(
    const float* __restrict__ W, double* __restrict__ part) {
  const int tid = threadIdx.x;
  const long base = (long)blockIdx.x * 8192;
  double s = 0.0;
#pragma unroll
  for (int c = 0; c < 8; ++c) {
    const float4 v = *(const float4*)&W[base + c * 1024 + tid * 4];
    s += (double)fabsf(v.x) + (double)fabsf(v.y) +
         (double)fabsf(v.z) + (double)fabsf(v.w);
  }
  __shared__ double sm[256];
  sm[tid] = s; __syncthreads();
  for (int off = 128; off; off >>= 1) {
    if (tid < off) sm[tid] += sm[tid + off];
    __syncthreads();
  }
  if (tid == 0) part[blockIdx.x] = sm[0];
}

__global__ __launch_bounds__(256) void absmean_final(
    const double* __restrict__ part, double* __restrict__ out, double n) {
  const int tid = threadIdx.x;
  __shared__ double sm[256];
  sm[tid] = part[tid] + part[tid + 256];
  __syncthreads();
  for (int off = 128; off; off >>= 1) {
    if (tid < off) sm[tid] += sm[tid + off];
    __syncthreads();
  }
  if (tid == 0) out[0] = fmax(sm[0] / n, 1e-5);
}

// --------------------------- weight ternarization ---------------------------
__global__ __launch_bounds__(256) void quant_w(
    const float* __restrict__ W, const double* __restrict__ wsP,
    signed char* __restrict__ Wq) {
  const double ws = *wsP;
  const long i = ((long)blockIdx.x * 256 + threadIdx.x) * 4;
  const float4 v = *(const float4*)&W[i];
  const float vv[4] = {v.x, v.y, v.z, v.w};
  int pack = 0;
#pragma unroll
  for (int q = 0; q < 4; ++q) {
    double r = rint((double)vv[q] / ws);  // RNE, matches jnp.round
    r = fmin(fmax(r, -1.0), 1.0);
    pack |= (((int)r) & 0xff) << (8 * q);
  }
  *(int*)&Wq[i] = pack;
}

// --------------------------- per-token activation quant ---------------------
template <int L, bool GELU, typename GT>
__global__ __launch_bounds__(256) void quant_rows(
    const GT* __restrict__ X, signed char* __restrict__ Xq,
    float* __restrict__ dsc) {
  constexpr int CH = L / 1024;
  const long row = blockIdx.x;
  const int tid = threadIdx.x;
  const GT* xr = X + row * (long)L;
  float v[CH][4];
  float m = 0.f;
#pragma unroll
  for (int c = 0; c < CH; ++c) {
    load4v(xr + c * 1024 + tid * 4, v[c]);
#pragma unroll
    for (int q = 0; q < 4; ++q) {
      if (GELU) v[c][q] = gelu_erf(v[c][q]);
      m = fmaxf(m, fabsf(v[c][q]));
    }
  }
#pragma unroll
  for (int off = 32; off; off >>= 1) m = fmaxf(m, __shfl_down(m, off, 64));
  __shared__ float wmx[4];
  if ((tid & 63) == 0) wmx[tid >> 6] = m;
  __syncthreads();
  float ms = fmaxf(fmaxf(wmx[0], wmx[1]), fmaxf(wmx[2], wmx[3]));
  ms = fmaxf(ms, 1e-5f);
  const double inv = 127.0 / (double)ms;
#pragma unroll
  for (int c = 0; c < CH; ++c) {
    int pack = 0;
#pragma unroll
    for (int q = 0; q < 4; ++q) {
      double r = rint((double)v[c][q] * inv);
      r = fmin(fmax(r, -128.0), 127.0);
      pack |= (((int)r) & 0xff) << (8 * q);
    }
    *(int*)&Xq[row * (long)L + c * 1024 + tid * 4] = pack;
  }
  if (tid == 0) dsc[row] = (float)((double)ms / 127.0);
}

// --------------------------- int8 GEMM, 2 blocks/CU -------------------------
// C[M][N] = A[M][K] * Bm[N][K]^T. 128x128 tile, BK=128, 4 waves (2x2),
// wave-tile 64x64. LDS 64KB: A dbuf at 0/16384, B dbuf at 32768/49152.
// Tile rows 128 B; swizzle: col ^= (row&7)<<4 (involution, both sides).
// Per-tile ledger: stage(t+1) [buf free: barrier R of t-1 proves reads of
// t-1 retired] -> vmcnt(8) [own stage(t) landed] -> barrier S [all waves'
// stage(t) landed] -> reads+MFMA -> lgkmcnt(0) -> barrier R.
template <typename GT>
__global__ __launch_bounds__(256, 2) void gemm_i8_occ(
    const signed char* __restrict__ A, const signed char* __restrict__ Bm,
    const float* __restrict__ dA, const double* __restrict__ wsB,
    const float* __restrict__ bias, GT* __restrict__ C,
    int K, int Ncol, int nx) {
  __shared__ signed char LDS[65536];
  const int tid = threadIdx.x;
  const int lane = tid & 63;
  const int wave = tid >> 6;
  const int wm = wave >> 1;  // 0..1
  const int wn = wave & 1;   // 0..1

  const int cpx = gridDim.x >> 3;
  const int wg = ((int)blockIdx.x & 7) * cpx + ((int)blockIdx.x >> 3);
  const long rowBase = (long)(wg / nx) * 128;
  const long colBase = (long)(wg % nx) * 128;
  const int NT = K >> 7;  // BK = 128

  // ---- staging: 4 x 16B per thread per matrix per K-tile ----
  const int dd = tid << 4;                          // [0,4096)
  const int srow = dd >> 7;                         // 0..31
  const int scol = (dd & 127) ^ ((srow & 7) << 4);  // pre-swizzled src col
  const long k32 = 32L * K;
  const signed char* sA0 = A + (rowBase + srow) * (long)K + scol;
  const signed char* sB0 = Bm + (colBase + srow) * (long)K + scol;

  auto STAGE = [&](int t) {
    const signed char* pa = sA0 + ((long)t << 7);
    const signed char* pb = sB0 + ((long)t << 7);
    signed char* la = &LDS[((t & 1) << 14) + dd];
    signed char* lb = &LDS[32768 + ((t & 1) << 14) + dd];
#pragma unroll
    for (int i = 0; i < 4; ++i) gload_lds16(pa + i * k32, la + i * 4096);
#pragma unroll
    for (int i = 0; i < 4; ++i) gload_lds16(pb + i * k32, lb + i * 4096);
  };

  // ---- ds_read fragment addressing ----
  const int rl = lane & 15;
  const int col0 = (((lane >> 4) << 4)) ^ ((rl & 7) << 4);  // swizzled col kc0
  const int aRow = wm * 8192 + rl * 128;  // within A tile
  const int bRow = wn * 8192 + rl * 128;  // within B tile

  int32x4 acc[4][4] = {};
  int32x4 af0[4], bf0[4], af1[4], bf1[4];

  // ---- prologue ----
  STAGE(0);

  for (int t = 0; t < NT; ++t) {
    const signed char* At = &LDS[(t & 1) << 14];
    const signed char* Bt = &LDS[32768 + ((t & 1) << 14)];

    // stage t+1 (buffer freed by barrier R of iter t-1)
    if (t + 1 < NT) {
      STAGE(t + 1);
      asm volatile("s_waitcnt vmcnt(8)" ::: "memory");  // own stage(t) landed
    } else {
      asm volatile("s_waitcnt vmcnt(0)" ::: "memory");
    }
    __builtin_amdgcn_s_barrier();  // S: all waves' stage(t) landed

    // reads: both kc halves up front; compiler interleaves with MFMA
#pragma unroll
    for (int i = 0; i < 4; ++i)
      af0[i] = *(const int32x4*)(At + aRow + i * 2048 + col0);
#pragma unroll
    for (int j = 0; j < 4; ++j)
      bf0[j] = *(const int32x4*)(Bt + bRow + j * 2048 + col0);
#pragma unroll
    for (int i = 0; i < 4; ++i)
      af1[i] = *(const int32x4*)(At + aRow + i * 2048 + (col0 ^ 64));
#pragma unroll
    for (int j = 0; j < 4; ++j)
      bf1[j] = *(const int32x4*)(Bt + bRow + j * 2048 + (col0 ^ 64));

    __builtin_amdgcn_s_setprio(1);
#pragma unroll
    for (int i = 0; i < 4; ++i)
#pragma unroll
      for (int j = 0; j < 4; ++j)
        acc[i][j] = __builtin_amdgcn_mfma_i32_16x16x64_i8(
            af0[i], bf0[j], acc[i][j], 0, 0, 0);
#pragma unroll
    for (int i = 0; i < 4; ++i)
#pragma unroll
      for (int j = 0; j < 4; ++j)
        acc[i][j] = __builtin_amdgcn_mfma_i32_16x16x64_i8(
            af1[i], bf1[j], acc[i][j], 0, 0, 0);
    __builtin_amdgcn_s_setprio(0);

    asm volatile("s_waitcnt lgkmcnt(0)" ::: "memory");  // reads retired
    __builtin_amdgcn_s_barrier();  // R: tile-t reads done in all waves
  }

  // ---- epilogue: C/D layout col=lane&15, row=(lane>>4)*4+reg ----
  const double wsd = *wsB;
  const int rq = (lane >> 4) << 2;
  float bv[4];
#pragma unroll
  for (int nj = 0; nj < 4; ++nj)
    bv[nj] = bias[colBase + wn * 64 + nj * 16 + rl];
#pragma unroll
  for (int mi = 0; mi < 4; ++mi) {
#pragma unroll
    for (int r = 0; r < 4; ++r) {
      const long row = rowBase + wm * 64 + mi * 16 + rq + r;
      const float sc = (float)((double)dA[row] * wsd);
      GT* crow = C + row * (long)Ncol + colBase + wn * 64 + rl;
#pragma unroll
      for (int nj = 0; nj < 4; ++nj)
        store_gt(&crow[nj * 16], (float)acc[mi][nj][r] * sc + bv[nj]);
    }
  }
}

// ---------------------------------------------------------------------------
extern "C" void kernel_launch(void* const* d_in, const int* in_sizes, int n_in,
                              void* d_out, int out_size, void* d_ws,
                              size_t ws_size, hipStream_t stream) {
  const float* x  = (const float*)d_in[0];
  const float* W1 = (const float*)d_in[1];
  const float* b1 = (const float*)d_in[2];
  const float* W2 = (const float*)d_in[3];
  const float* b2 = (const float*)d_in[4];
  const int D = in_sizes[4];             // 1024
  const int H = in_sizes[2];             // 4096
  const long M = (long)in_sizes[0] / D;  // 32768
  float* out = (float*)d_out;

  if (D != 1024 || H != 4096 || (M % 128) != 0) return;  // shape contract

  char* wsp = (char*)d_ws;
  size_t off = 0;
  auto alloc = [&](size_t bytes) {
    void* p = wsp + off;
    off = (off + bytes + 255) & ~(size_t)255;
    return p;
  };
  signed char* wq1 = (signed char*)alloc((size_t)H * D);
  signed char* wq2 = (signed char*)alloc((size_t)D * H);
  signed char* xq  = (signed char*)alloc((size_t)M * D);
  signed char* gq  = (signed char*)alloc((size_t)M * H);
  float* dx = (float*)alloc((size_t)M * 4);
  float* dg = (float*)alloc((size_t)M * 4);
  double* part = (double*)alloc(512 * 8);
  double* ws1 = (double*)alloc(8);
  double* ws2 = (double*)alloc(8);
  __hip_bfloat16* h = (__hip_bfloat16*)alloc((size_t)M * H * 2);
  if (off > ws_size) return;  // cannot run

  const long nW = (long)H * D;
  absmean_partial<<<nW / 8192, 256, 0, stream>>>(W1, part);
  absmean_final<<<1, 256, 0, stream>>>(part, ws1, (double)nW);
  absmean_partial<<<nW / 8192, 256, 0, stream>>>(W2, part);
  absmean_final<<<1, 256, 0, stream>>>(part, ws2, (double)nW);
  quant_w<<<nW / 1024, 256, 0, stream>>>(W1, ws1, wq1);
  quant_w<<<nW / 1024, 256, 0, stream>>>(W2, ws2, wq2);
  quant_rows<1024, false, float><<<M, 256, 0, stream>>>(x, xq, dx);

  const int g1 = (int)(M / 128) * (H / 128);  // 8192
  const int g2 = (int)(M / 128) * (D / 128);  // 2048
  gemm_i8_occ<__hip_bfloat16><<<g1, 256, 0, stream>>>(
      xq, wq1, dx, ws1, b1, h, D, H, H / 128);
  quant_rows<4096, true, __hip_bfloat16><<<M, 256, 0, stream>>>(h, gq, dg);
  gemm_i8_occ<float><<<g2, 256, 0, stream>>>(
      gq, wq2, dg, ws2, b2, out, H, D, D / 128);
}

// Round 8
// 499.070 us; speedup vs baseline: 1.0348x; 1.0348x over previous
//
#include <hip/hip_runtime.h>
#include <hip/hip_bf16.h>
#include <math.h>

// ---------------------------------------------------------------------------
// BitNet-b1.58 MLP: x -> bitlinear(W1,b1) -> gelu(erf) -> bitlinear(W2,b2)
// Exact-integer formulation: int8 x int8 -> int32 MFMA, dequant in epilogue.
// GEMM r8: 128x256 tile, BK=64, 512 thr (8 waves, wave 64x64, acc 64 regs),
// LDS 48KB dbuf -> 2 blocks/CU (the r7-proven 1.8x staging-rate lever) with
// 256-col reuse restored. r2 ledger: stage(t+1) -> vmcnt(3) -> barrier ->
// reads -> 16 MFMA -> lgkm0 -> barrier. 64B-row swizzle slot^=(row&3).
// ---------------------------------------------------------------------------

typedef int int32x4 __attribute__((ext_vector_type(4)));

typedef const void __attribute__((address_space(1))) gv_t;
typedef void __attribute__((address_space(3))) lv_t;

__device__ __forceinline__ void gload_lds16(const signed char* g,
                                            signed char* l) {
  __builtin_amdgcn_global_load_lds((gv_t*)g, (lv_t*)l, 16, 0, 0);
}

__device__ __forceinline__ float gelu_erf(float v) {
  return 0.5f * v * (1.0f + erff(v * 0.70710678118654752440f));
}

__device__ __forceinline__ void store_gt(float* p, float v) { *p = v; }
__device__ __forceinline__ void store_gt(__hip_bfloat16* p, float v) {
  unsigned u = __float_as_uint(v);
  u += 0x7fffu + ((u >> 16) & 1u);  // RNE to bf16
  *(unsigned short*)p = (unsigned short)(u >> 16);
}

__device__ __forceinline__ void load4v(const float* p, float v[4]) {
  const float4 t = *(const float4*)p;
  v[0] = t.x; v[1] = t.y; v[2] = t.z; v[3] = t.w;
}
__device__ __forceinline__ void load4v(const __hip_bfloat16* p, float v[4]) {
  const ushort4 t = *(const ushort4*)p;
  v[0] = __uint_as_float((unsigned)t.x << 16);
  v[1] = __uint_as_float((unsigned)t.y << 16);
  v[2] = __uint_as_float((unsigned)t.z << 16);
  v[3] = __uint_as_float((unsigned)t.w << 16);
}

// --------------------------- w_scale reduction ------------------------------
__global__ __launch_bounds__(256) void absmean_partial(
    const float* __restrict__ W, double* __restrict__ part) {
  const int tid = threadIdx.x;
  const long base = (long)blockIdx.x * 8192;
  double s = 0.0;
#pragma unroll
  for (int c = 0; c < 8; ++c) {
    const float4 v = *(const float4*)&W[base + c * 1024 + tid * 4];
    s += (double)fabsf(v.x) + (double)fabsf(v.y) +
         (double)fabsf(v.z) + (double)fabsf(v.w);
  }
  __shared__ double sm[256];
  sm[tid] = s; __syncthreads();
  for (int off = 128; off; off >>= 1) {
    if (tid < off) sm[tid] += sm[tid + off];
    __syncthreads();
  }
  if (tid == 0) part[blockIdx.x] = sm[0];
}

__global__ __launch_bounds__(256) void absmean_final(
    const double* __restrict__ part, double* __restrict__ out, double n) {
  const int tid = threadIdx.x;
  __shared__ double sm[256];
  sm[tid] = part[tid] + part[tid + 256];
  __syncthreads();
  for (int off = 128; off; off >>= 1) {
    if (tid < off) sm[tid] += sm[tid + off];
    __syncthreads();
  }
  if (tid == 0) out[0] = fmax(sm[0] / n, 1e-5);
}

// --------------------------- weight ternarization ---------------------------
__global__ __launch_bounds__(256) void quant_w(
    const float* __restrict__ W, const double* __restrict__ wsP,
    signed char* __restrict__ Wq) {
  const double ws = *wsP;
  const long i = ((long)blockIdx.x * 256 + threadIdx.x) * 4;
  const float4 v = *(const float4*)&W[i];
  const float vv[4] = {v.x, v.y, v.z, v.w};
  int pack = 0;
#pragma unroll
  for (int q = 0; q < 4; ++q) {
    double r = rint((double)vv[q] / ws);  // RNE, matches jnp.round
    r = fmin(fmax(r, -1.0), 1.0);
    pack |= (((int)r) & 0xff) << (8 * q);
  }
  *(int*)&Wq[i] = pack;
}

// --------------------------- per-token activation quant ---------------------
template <int L, bool GELU, typename GT>
__global__ __launch_bounds__(256) void quant_rows(
    const GT* __restrict__ X, signed char* __restrict__ Xq,
    float* __restrict__ dsc) {
  constexpr int CH = L / 1024;
  const long row = blockIdx.x;
  const int tid = threadIdx.x;
  const GT* xr = X + row * (long)L;
  float v[CH][4];
  float m = 0.f;
#pragma unroll
  for (int c = 0; c < CH; ++c) {
    load4v(xr + c * 1024 + tid * 4, v[c]);
#pragma unroll
    for (int q = 0; q < 4; ++q) {
      if (GELU) v[c][q] = gelu_erf(v[c][q]);
      m = fmaxf(m, fabsf(v[c][q]));
    }
  }
#pragma unroll
  for (int off = 32; off; off >>= 1) m = fmaxf(m, __shfl_down(m, off, 64));
  __shared__ float wmx[4];
  if ((tid & 63) == 0) wmx[tid >> 6] = m;
  __syncthreads();
  float ms = fmaxf(fmaxf(wmx[0], wmx[1]), fmaxf(wmx[2], wmx[3]));
  ms = fmaxf(ms, 1e-5f);
  const double inv = 127.0 / (double)ms;
#pragma unroll
  for (int c = 0; c < CH; ++c) {
    int pack = 0;
#pragma unroll
    for (int q = 0; q < 4; ++q) {
      double r = rint((double)v[c][q] * inv);
      r = fmin(fmax(r, -128.0), 127.0);
      pack |= (((int)r) & 0xff) << (8 * q);
    }
    *(int*)&Xq[row * (long)L + c * 1024 + tid * 4] = pack;
  }
  if (tid == 0) dsc[row] = (float)((double)ms / 127.0);
}

// --------------------------- int8 GEMM, 2 blocks/CU, 128x256 ---------------
// C[M][N] = A[M][K] * Bm[N][K]^T. Tile 128(M) x 256(N), BK=64 (64B rows).
// LDS 48KB: A dbuf [0,16K) (8KB each), B dbuf [16K,48K) (16KB each).
// Swizzle (16B slots in 64B rows): slot ^= (row&3); staging sources
// pre-swizzled, gload_lds dest strictly linear (base + lane*16).
// Ledger/tile: stage(t+1) -> vmcnt(3) [own stage(t) landed] -> barrier S
// -> 8 ds_read_b128 -> 16 MFMA -> lgkmcnt(0) -> barrier R [buf freed].
template <typename GT>
__global__ __launch_bounds__(512, 4) void gemm_i8_2b(
    const signed char* __restrict__ A, const signed char* __restrict__ Bm,
    const float* __restrict__ dA, const double* __restrict__ wsB,
    const float* __restrict__ bias, GT* __restrict__ C,
    int K, int Ncol, int nx) {
  __shared__ signed char LDS[49152];
  const int tid = threadIdx.x;
  const int lane = tid & 63;
  const int wave = tid >> 6;
  const int wm = wave >> 2;  // 0..1  (M half)
  const int wn = wave & 3;   // 0..3  (N quarter)

  const int cpx = gridDim.x >> 3;
  const int wg = ((int)blockIdx.x & 7) * cpx + ((int)blockIdx.x >> 3);
  const long rowBase = (long)(wg / nx) * 128;
  const long colBase = (long)(wg % nx) * 256;
  const int NT = K >> 6;  // BK = 64

  // ---- staging sources (per thread, 3 gloads/tile, dest = linear tid*16) --
  const int sr = tid >> 2;                            // 0..127
  const int sc = ((tid & 3) << 4) ^ ((sr & 3) << 4);  // pre-swizzled col
  const signed char* gAr = A + (rowBase + sr) * (long)K + sc;
  const signed char* gBr = Bm + (colBase + sr) * (long)K + sc;
  const signed char* gBr2 = gBr + 128L * K;
  const int da = tid << 4;

  auto STAGE = [&](int t) {
    const long ko = (long)t << 6;
    gload_lds16(gAr + ko, &LDS[((t & 1) << 13) + da]);
    gload_lds16(gBr + ko, &LDS[16384 + ((t & 1) << 14) + da]);
    gload_lds16(gBr2 + ko, &LDS[16384 + ((t & 1) << 14) + 8192 + da]);
  };

  // ---- ds_read fragment addressing (64B rows, swizzled 16B slot) ----------
  const int rl = lane & 15;
  const int axor = (((lane >> 4) ^ (rl & 3)) << 4);
  const int aoff = (wm * 64 + rl) * 64 + axor;  // + mi*1024
  const int boff = (wn * 64 + rl) * 64 + axor;  // + nj*1024

  int32x4 acc[4][4] = {};
  int32x4 af[4], bf[4];

  STAGE(0);

  for (int t = 0; t < NT; ++t) {
    if (t + 1 < NT) {
      STAGE(t + 1);
      asm volatile("s_waitcnt vmcnt(3)" ::: "memory");  // stage(t) landed
    } else {
      asm volatile("s_waitcnt vmcnt(0)" ::: "memory");
    }
    __builtin_amdgcn_s_barrier();  // S: tile t resident for all waves

    const signed char* At = &LDS[(t & 1) << 13];
    const signed char* Bt = &LDS[16384 + ((t & 1) << 14)];
#pragma unroll
    for (int mi = 0; mi < 4; ++mi)
      af[mi] = *(const int32x4*)(At + aoff + mi * 1024);
#pragma unroll
    for (int nj = 0; nj < 4; ++nj)
      bf[nj] = *(const int32x4*)(Bt + boff + nj * 1024);

    __builtin_amdgcn_s_setprio(1);
#pragma unroll
    for (int mi = 0; mi < 4; ++mi)
#pragma unroll
      for (int nj = 0; nj < 4; ++nj)
        acc[mi][nj] = __builtin_amdgcn_mfma_i32_16x16x64_i8(
            af[mi], bf[nj], acc[mi][nj], 0, 0, 0);
    __builtin_amdgcn_s_setprio(0);

    asm volatile("s_waitcnt lgkmcnt(0)" ::: "memory");  // reads retired
    __builtin_amdgcn_s_barrier();  // R: buffer (t&1) free for overwrite
  }

  // ---- epilogue: C/D layout col=lane&15, row=(lane>>4)*4+reg ----
  const double wsd = *wsB;
  const int rq = (lane >> 4) << 2;
  float bv[4];
#pragma unroll
  for (int nj = 0; nj < 4; ++nj)
    bv[nj] = bias[colBase + wn * 64 + nj * 16 + rl];
#pragma unroll
  for (int mi = 0; mi < 4; ++mi) {
#pragma unroll
    for (int r = 0; r < 4; ++r) {
      const long row = rowBase + wm * 64 + mi * 16 + rq + r;
      const float sc2 = (float)((double)dA[row] * wsd);
      GT* crow = C + row * (long)Ncol + colBase + wn * 64 + rl;
#pragma unroll
      for (int nj = 0; nj < 4; ++nj)
        store_gt(&crow[nj * 16], (float)acc[mi][nj][r] * sc2 + bv[nj]);
    }
  }
}

// ---------------------------------------------------------------------------
extern "C" void kernel_launch(void* const* d_in, const int* in_sizes, int n_in,
                              void* d_out, int out_size, void* d_ws,
                              size_t ws_size, hipStream_t stream) {
  const float* x  = (const float*)d_in[0];
  const float* W1 = (const float*)d_in[1];
  const float* b1 = (const float*)d_in[2];
  const float* W2 = (const float*)d_in[3];
  const float* b2 = (const float*)d_in[4];
  const int D = in_sizes[4];             // 1024
  const int H = in_sizes[2];             // 4096
  const long M = (long)in_sizes[0] / D;  // 32768
  float* out = (float*)d_out;

  if (D != 1024 || H != 4096 || (M % 128) != 0) return;  // shape contract

  char* wsp = (char*)d_ws;
  size_t off = 0;
  auto alloc = [&](size_t bytes) {
    void* p = wsp + off;
    off = (off + bytes + 255) & ~(size_t)255;
    return p;
  };
  signed char* wq1 = (signed char*)alloc((size_t)H * D);
  signed char* wq2 = (signed char*)alloc((size_t)D * H);
  signed char* xq  = (signed char*)alloc((size_t)M * D);
  signed char* gq  = (signed char*)alloc((size_t)M * H);
  float* dx = (float*)alloc((size_t)M * 4);
  float* dg = (float*)alloc((size_t)M * 4);
  double* part = (double*)alloc(512 * 8);
  double* ws1 = (double*)alloc(8);
  double* ws2 = (double*)alloc(8);
  __hip_bfloat16* h = (__hip_bfloat16*)alloc((size_t)M * H * 2);
  if (off > ws_size) return;  // cannot run

  const long nW = (long)H * D;
  absmean_partial<<<nW / 8192, 256, 0, stream>>>(W1, part);
  absmean_final<<<1, 256, 0, stream>>>(part, ws1, (double)nW);
  absmean_partial<<<nW / 8192, 256, 0, stream>>>(W2, part);
  absmean_final<<<1, 256, 0, stream>>>(part, ws2, (double)nW);
  quant_w<<<nW / 1024, 256, 0, stream>>>(W1, ws1, wq1);
  quant_w<<<nW / 1024, 256, 0, stream>>>(W2, ws2, wq2);
  quant_rows<1024, false, float><<<M, 256, 0, stream>>>(x, xq, dx);

  const int g1 = (int)(M / 128) * (H / 256);  // 4096
  const int g2 = (int)(M / 128) * (D / 256);  // 1024
  gemm_i8_2b<__hip_bfloat16><<<g1, 512, 0, stream>>>(
      xq, wq1, dx, ws1, b1, h, D, H, H / 256);
  quant_rows<4096, true, __hip_bfloat16><<<M, 256, 0, stream>>>(h, gq, dg);
  gemm_i8_2b<float><<<g2, 512, 0, stream>>>(
      gq, wq2, dg, ws2, b2, out, H, D, D / 256);
}